// Round 8
// baseline (293.370 us; speedup 1.0000x reference)
//
#include <hip/hip_runtime.h>
#include <math.h>
#include <float.h>

#define B_ 1024
#define R_ 12
#define N_ 2048

typedef float floatx4 __attribute__((ext_vector_type(4)));

// ---------------------------------------------------------------------------
// const_kernel (1 block, 1024 thr):
//   M[i,j] = Wq2[i,:] . Wk2[j,:]   (32x32)
//   v[j]   = Wk2[j,:] . bq2        u[i] = Wq2[i,:] . bk2       k0 = bq2 . bk2
//   WkT[j][0..10] = Wk1[t][j],  WkT[j][11] = bk1[j]   (32x12, row-contiguous)
// ---------------------------------------------------------------------------
__global__ void __launch_bounds__(1024) const_kernel(
    const float* __restrict__ Wq2, const float* __restrict__ bq2,
    const float* __restrict__ Wk2, const float* __restrict__ bk2,
    const float* __restrict__ Wk1, const float* __restrict__ bk1,
    float* __restrict__ Mmat, float* __restrict__ uvec,
    float* __restrict__ vvec, float* __restrict__ k0p,
    float* __restrict__ WkT)
{
    const int t = threadIdx.x;
    const int i = t >> 5, j = t & 31;
    float m = 0.0f;
    for (int d = 0; d < 64; d++) m += Wq2[i * 64 + d] * Wk2[j * 64 + d];
    Mmat[t] = m;
    if (t < 32) {
        float v = 0.0f;
        for (int d = 0; d < 64; d++) v += Wk2[t * 64 + d] * bq2[d];
        vvec[t] = v;
    } else if (t < 64) {
        float u = 0.0f;
        for (int d = 0; d < 64; d++) u += Wq2[(t - 32) * 64 + d] * bk2[d];
        uvec[t - 32] = u;
    } else if (t == 64) {
        float k = 0.0f;
        for (int d = 0; d < 64; d++) k += bq2[d] * bk2[d];
        k0p[0] = k;
    }
    if (t < 384) {
        const int jj = t / 12, e = t - jj * 12;
        WkT[t] = (e < 11) ? Wk1[e * 32 + jj] : bk1[jj];
    }
}

// ---------------------------------------------------------------------------
// prep_kernel: ONE thread per (b,r).  Q held as named floatx4 Q0..Q7 (no
// arrays -> registers).  M rows are wave-uniform -> wide s_load.  Writes the
// TRANSPOSED qpT[b][j][r] layout main stages from.  Packs mask bits too.
// ---------------------------------------------------------------------------
__global__ void __launch_bounds__(256) prep_kernel(
    const float* __restrict__ rss,                       // [B*R]
    const float* __restrict__ Wg1, const float* __restrict__ bg1,
    const float* __restrict__ Wg2, const float* __restrict__ bg2,
    const float* __restrict__ Wq1, const float* __restrict__ bq1,
    const float* __restrict__ Mmat, const float* __restrict__ uvec,
    const float* __restrict__ vvec, const float* __restrict__ k0p,
    const int*   __restrict__ mask,                      // [R,N]
    float* __restrict__ qpT,                             // [B][32][12]
    float* __restrict__ cc,                              // [B*R]
    int*   __restrict__ maskbits,                        // [N]
    float* __restrict__ inten_out)                       // [B*R]
{
    const int gt = blockIdx.x * 256 + threadIdx.x;

    if (gt < N_) {
        int bits = 0;
#pragma unroll
        for (int r = 0; r < R_; r++) bits |= (mask[r * N_ + gt] != 0) << r;
        maskbits[gt] = bits;
    }

    if (gt >= B_ * R_) return;
    const int b = gt / 12, r = gt - b * 12;

    const float x = rss[gt];
    const float hard = (x > 0.5f) ? 1.0f : 0.0f;

    float s2 = bg2[0];
#pragma unroll
    for (int i = 0; i < 16; i++)
        s2 += fmaxf(x * Wg1[i] + bg1[i], 0.0f) * Wg2[i];
    const float gate = 1.0f / (1.0f + __expf(-s2));
    const float iw = hard * gate;
    const float xm = x * iw;

    const floatx4* vv = reinterpret_cast<const floatx4*>(vvec);
    floatx4 Q0 = vv[0], Q1 = vv[1], Q2 = vv[2], Q3 = vv[3];
    floatx4 Q4 = vv[4], Q5 = vv[5], Q6 = vv[6], Q7 = vv[7];
    float c = k0p[0];

#pragma unroll
    for (int i = 0; i < 32; i++) {
        const float h = fmaxf(xm * Wq1[i] + bq1[i], 0.0f);
        const floatx4* mr = reinterpret_cast<const floatx4*>(Mmat + i * 32);
        Q0 += h * mr[0]; Q1 += h * mr[1]; Q2 += h * mr[2]; Q3 += h * mr[3];
        Q4 += h * mr[4]; Q5 += h * mr[5]; Q6 += h * mr[6]; Q7 += h * mr[7];
        c  += h * uvec[i];
    }

    // transposed store: qpT[b*384 + j*12 + r]
    float* qb = qpT + (size_t)b * 384 + r;
#define STQ(k)                          \
    qb[(4 * k + 0) * 12] = Q##k.x;      \
    qb[(4 * k + 1) * 12] = Q##k.y;      \
    qb[(4 * k + 2) * 12] = Q##k.z;      \
    qb[(4 * k + 3) * 12] = Q##k.w;
    STQ(0) STQ(1) STQ(2) STQ(3) STQ(4) STQ(5) STQ(6) STQ(7)
#undef STQ

    cc[gt] = c;
    inten_out[gt] = iw;
}

// ---------------------------------------------------------------------------
// main_kernel: one block per batch b, 512 threads, 4 LEDs/thread (lanes of
// floatx4).  Weights staged ONCE into LDS in transposed row-contiguous form;
// the j-loop reads 6 uniform ds_read_b128 per j (broadcast, conflict-free).
// All private state is named vectors -> zero scratch.
// ---------------------------------------------------------------------------
__global__ void __launch_bounds__(512, 2) main_kernel(
    const float* __restrict__ ledf,     // [B,N,8]
    const float* __restrict__ ledp,     // [B,N,3]
    const float* __restrict__ prevp,    // [B,3]
    const int*   __restrict__ maskbits, // [N]
    const float* __restrict__ WkT,      // [32][12]
    const float* __restrict__ qpT,      // [B][32][12]
    const float* __restrict__ cc,       // [B*R]
    const float* __restrict__ sigp,     // [1]
    float* __restrict__ out)            // [B,R,N]
{
    const int b = blockIdx.x;
    const int tid = threadIdx.x;
    const int lane = tid & 63;
    const int wave = tid >> 6;
    const int n0 = tid * 4;

    __shared__ float sW[32 * 12];
    __shared__ float sQ[32 * 12];
    __shared__ float red[8 * 12];

    if (tid < 384) {
        sW[tid] = WkT[tid];
        sQ[tid] = qpT[(size_t)b * 384 + tid];
    }

    const float* __restrict__ ccb = cc + b * 12;
    const float sig = sigp[0];
    const float nfc = -0.5f / (sig * sig);
    const float p0 = prevp[b * 3 + 0];
    const float p1 = prevp[b * 3 + 1];
    const float p2 = prevp[b * 3 + 2];

    const floatx4* pf = reinterpret_cast<const floatx4*>(ledf + ((size_t)b * N_ + n0) * 8);
    const floatx4* pp4 = reinterpret_cast<const floatx4*>(ledp + ((size_t)b * N_ + n0) * 3);
    const floatx4 F0 = pf[0], F1 = pf[1], F2 = pf[2], F3 = pf[3];
    const floatx4 F4 = pf[4], F5 = pf[5], F6 = pf[6], F7 = pf[7];
    const floatx4 pa = pp4[0], pb = pp4[1], pc = pp4[2];
    const int4 mb = *reinterpret_cast<const int4*>(maskbits + n0);

    const floatx4 X0 = {F0.x, F2.x, F4.x, F6.x};
    const floatx4 X1 = {F0.y, F2.y, F4.y, F6.y};
    const floatx4 X2 = {F0.z, F2.z, F4.z, F6.z};
    const floatx4 X3 = {F0.w, F2.w, F4.w, F6.w};
    const floatx4 X4 = {F1.x, F3.x, F5.x, F7.x};
    const floatx4 X5 = {F1.y, F3.y, F5.y, F7.y};
    const floatx4 X6 = {F1.z, F3.z, F5.z, F7.z};
    const floatx4 X7 = {F1.w, F3.w, F5.w, F7.w};
    const floatx4 X8 = {pa.x, pa.w, pb.z, pc.y};
    const floatx4 X9 = {pa.y, pb.x, pb.w, pc.z};
    const floatx4 X10 = {pa.z, pb.y, pc.x, pc.w};

    const floatx4 DX = p0 - X8, DY = p1 - X9, DZ = p2 - X10;
    const floatx4 BIAS = nfc * (DX * DX + DY * DY + DZ * DZ);

#define FOR_R(OP) OP(0) OP(1) OP(2) OP(3) OP(4) OP(5) OP(6) OP(7) OP(8) OP(9) OP(10) OP(11)
#define INIT_R(r) floatx4 A##r = BIAS + ccb[r];
    FOR_R(INIT_R)

    __syncthreads();   // staging done

#pragma unroll 4
    for (int j = 0; j < 32; j++) {
        const floatx4 w0 = *reinterpret_cast<const floatx4*>(&sW[j * 12]);
        const floatx4 w1 = *reinterpret_cast<const floatx4*>(&sW[j * 12 + 4]);
        const floatx4 w2 = *reinterpret_cast<const floatx4*>(&sW[j * 12 + 8]); // {w8,w9,w10,bj}
        const floatx4 q0 = *reinterpret_cast<const floatx4*>(&sQ[j * 12]);
        const floatx4 q1 = *reinterpret_cast<const floatx4*>(&sQ[j * 12 + 4]);
        const floatx4 q2 = *reinterpret_cast<const floatx4*>(&sQ[j * 12 + 8]);

        floatx4 H = {w2.w, w2.w, w2.w, w2.w};
        H += X0 * w0.x;  H += X1 * w0.y;  H += X2 * w0.z;  H += X3 * w0.w;
        H += X4 * w1.x;  H += X5 * w1.y;  H += X6 * w1.z;  H += X7 * w1.w;
        H += X8 * w2.x;  H += X9 * w2.y;  H += X10 * w2.z;
        H.x = fmaxf(H.x, 0.0f);
        H.y = fmaxf(H.y, 0.0f);
        H.z = fmaxf(H.z, 0.0f);
        H.w = fmaxf(H.w, 0.0f);

        A0 += H * q0.x;  A1 += H * q0.y;  A2  += H * q0.z;  A3  += H * q0.w;
        A4 += H * q1.x;  A5 += H * q1.y;  A6  += H * q1.z;  A7  += H * q1.w;
        A8 += H * q2.x;  A9 += H * q2.y;  A10 += H * q2.z;  A11 += H * q2.w;
    }

#define MASK_R(r)                                      \
    A##r.x = ((mb.x >> r) & 1) ? A##r.x : -FLT_MAX;    \
    A##r.y = ((mb.y >> r) & 1) ? A##r.y : -FLT_MAX;    \
    A##r.z = ((mb.z >> r) & 1) ? A##r.z : -FLT_MAX;    \
    A##r.w = ((mb.w >> r) & 1) ? A##r.w : -FLT_MAX;
    FOR_R(MASK_R)

#define WMAX_R(r) {                                                     \
    float v = fmaxf(fmaxf(A##r.x, A##r.y), fmaxf(A##r.z, A##r.w));      \
    _Pragma("unroll")                                                   \
    for (int off = 32; off >= 1; off >>= 1) v = fmaxf(v, __shfl_xor(v, off)); \
    if (lane == 0) red[wave * 12 + r] = v; }
    FOR_R(WMAX_R)
    __syncthreads();
#define FMAX_R(r) float M##r = red[r];                                  \
    { _Pragma("unroll")                                                 \
      for (int w = 1; w < 8; w++) M##r = fmaxf(M##r, red[w * 12 + r]); }
    FOR_R(FMAX_R)
    __syncthreads();

#define EXP_R(r) {                                                      \
    A##r.x = __expf(A##r.x - M##r); A##r.y = __expf(A##r.y - M##r);     \
    A##r.z = __expf(A##r.z - M##r); A##r.w = __expf(A##r.w - M##r);     \
    float v = (A##r.x + A##r.y) + (A##r.z + A##r.w);                    \
    _Pragma("unroll")                                                   \
    for (int off = 32; off >= 1; off >>= 1) v += __shfl_xor(v, off);    \
    if (lane == 0) red[wave * 12 + r] = v; }
    FOR_R(EXP_R)
    __syncthreads();
#define FSUM_R(r) float S##r = red[r];                                  \
    { _Pragma("unroll")                                                 \
      for (int w = 1; w < 8; w++) S##r += red[w * 12 + r]; }            \
    S##r = 1.0f / S##r;
    FOR_R(FSUM_R)

    float* outp = out + (size_t)b * R_ * N_ + n0;
#define STORE_R(r) {                                                    \
    floatx4 v = A##r * S##r;                                            \
    __builtin_nontemporal_store(v, reinterpret_cast<floatx4*>(outp + (size_t)r * N_)); }
    FOR_R(STORE_R)
}

// ---------------------------------------------------------------------------
extern "C" void kernel_launch(void* const* d_in, const int* in_sizes, int n_in,
                              void* d_out, int out_size, void* d_ws, size_t ws_size,
                              hipStream_t stream) {
    const float* rss  = (const float*)d_in[0];
    const float* ledf = (const float*)d_in[1];
    const float* ledp = (const float*)d_in[2];
    const float* prevp= (const float*)d_in[3];
    const int*   mask = (const int*)  d_in[4];
    const float* Wg1  = (const float*)d_in[5];
    const float* bg1  = (const float*)d_in[6];
    const float* Wg2  = (const float*)d_in[7];
    const float* bg2  = (const float*)d_in[8];
    const float* Wq1  = (const float*)d_in[9];
    const float* bq1  = (const float*)d_in[10];
    const float* Wq2  = (const float*)d_in[11];
    const float* bq2  = (const float*)d_in[12];
    const float* Wk1  = (const float*)d_in[13];
    const float* bk1  = (const float*)d_in[14];
    const float* Wk2  = (const float*)d_in[15];
    const float* bk2  = (const float*)d_in[16];
    const float* sigp = (const float*)d_in[17];

    float* out = (float*)d_out;
    float* inten = out + (size_t)B_ * R_ * N_;     // intensity_weight [B,R] tail

    float* qpT      = (float*)d_ws;                // [B][32][12]
    float* cc       = qpT + (size_t)B_ * 384;      // [B*R]
    int*   maskbits = (int*)(cc + B_ * R_);        // [N]
    float* Mmat     = (float*)(maskbits + N_);     // [32,32]
    float* uvec     = Mmat + 1024;                 // [32]
    float* vvec     = uvec + 32;                   // [32]
    float* k0p      = vvec + 32;                   // [1]
    float* WkT      = k0p + 4;                     // [32*12] (keep 16B align)

    const_kernel<<<1, 1024, 0, stream>>>(Wq2, bq2, Wk2, bk2, Wk1, bk1,
                                         Mmat, uvec, vvec, k0p, WkT);

    prep_kernel<<<(B_ * R_ + 255) / 256, 256, 0, stream>>>(
        rss, Wg1, bg1, Wg2, bg2, Wq1, bq1,
        Mmat, uvec, vvec, k0p, mask, qpT, cc, maskbits, inten);

    main_kernel<<<B_, 512, 0, stream>>>(
        ledf, ledp, prevp, maskbits, WkT, qpT, cc, sigp, out);
}

// Round 9
// 275.447 us; speedup vs baseline: 1.0651x; 1.0651x over previous
//
#include <hip/hip_runtime.h>
#include <math.h>
#include <float.h>

#define B_ 1024
#define R_ 12
#define N_ 2048

typedef float floatx4 __attribute__((ext_vector_type(4)));

// ---------------------------------------------------------------------------
// const_kernel (1 block, 1024 thr):
//   M[i,j] = Wq2[i,:] . Wk2[j,:]   (32x32)
//   v[j]   = Wk2[j,:] . bq2        u[i] = Wq2[i,:] . bk2       k0 = bq2 . bk2
//   WkT[j][0..10] = Wk1[t][j],  WkT[j][11] = bk1[j]   (32x12, row-contiguous)
// ---------------------------------------------------------------------------
__global__ void __launch_bounds__(1024) const_kernel(
    const float* __restrict__ Wq2, const float* __restrict__ bq2,
    const float* __restrict__ Wk2, const float* __restrict__ bk2,
    const float* __restrict__ Wk1, const float* __restrict__ bk1,
    float* __restrict__ Mmat, float* __restrict__ uvec,
    float* __restrict__ vvec, float* __restrict__ k0p,
    float* __restrict__ WkT)
{
    const int t = threadIdx.x;
    const int i = t >> 5, j = t & 31;
    float m = 0.0f;
    for (int d = 0; d < 64; d++) m += Wq2[i * 64 + d] * Wk2[j * 64 + d];
    Mmat[t] = m;
    if (t < 32) {
        float v = 0.0f;
        for (int d = 0; d < 64; d++) v += Wk2[t * 64 + d] * bq2[d];
        vvec[t] = v;
    } else if (t < 64) {
        float u = 0.0f;
        for (int d = 0; d < 64; d++) u += Wq2[(t - 32) * 64 + d] * bk2[d];
        uvec[t - 32] = u;
    } else if (t == 64) {
        float k = 0.0f;
        for (int d = 0; d < 64; d++) k += bq2[d] * bk2[d];
        k0p[0] = k;
    }
    if (t < 384) {
        const int jj = t / 12, e = t - jj * 12;
        WkT[t] = (e < 11) ? Wk1[e * 32 + jj] : bk1[jj];
    }
}

// ---------------------------------------------------------------------------
// prep_kernel: ONE thread per (b,r).  Q held as named floatx4 Q0..Q7 (no
// arrays -> registers).  Writes TRANSPOSED qpT[b][j][r].  Packs mask bits.
// ---------------------------------------------------------------------------
__global__ void __launch_bounds__(256) prep_kernel(
    const float* __restrict__ rss,                       // [B*R]
    const float* __restrict__ Wg1, const float* __restrict__ bg1,
    const float* __restrict__ Wg2, const float* __restrict__ bg2,
    const float* __restrict__ Wq1, const float* __restrict__ bq1,
    const float* __restrict__ Mmat, const float* __restrict__ uvec,
    const float* __restrict__ vvec, const float* __restrict__ k0p,
    const int*   __restrict__ mask,                      // [R,N]
    float* __restrict__ qpT,                             // [B][32][12]
    float* __restrict__ cc,                              // [B*R]
    int*   __restrict__ maskbits,                        // [N]
    float* __restrict__ inten_out)                       // [B*R]
{
    const int gt = blockIdx.x * 256 + threadIdx.x;

    if (gt < N_) {
        int bits = 0;
#pragma unroll
        for (int r = 0; r < R_; r++) bits |= (mask[r * N_ + gt] != 0) << r;
        maskbits[gt] = bits;
    }

    if (gt >= B_ * R_) return;
    const int b = gt / 12, r = gt - b * 12;

    const float x = rss[gt];
    const float hard = (x > 0.5f) ? 1.0f : 0.0f;

    float s2 = bg2[0];
#pragma unroll
    for (int i = 0; i < 16; i++)
        s2 += fmaxf(x * Wg1[i] + bg1[i], 0.0f) * Wg2[i];
    const float gate = 1.0f / (1.0f + __expf(-s2));
    const float iw = hard * gate;
    const float xm = x * iw;

    const floatx4* vv = reinterpret_cast<const floatx4*>(vvec);
    floatx4 Q0 = vv[0], Q1 = vv[1], Q2 = vv[2], Q3 = vv[3];
    floatx4 Q4 = vv[4], Q5 = vv[5], Q6 = vv[6], Q7 = vv[7];
    float c = k0p[0];

#pragma unroll
    for (int i = 0; i < 32; i++) {
        const float h = fmaxf(xm * Wq1[i] + bq1[i], 0.0f);
        const floatx4* mr = reinterpret_cast<const floatx4*>(Mmat + i * 32);
        Q0 += h * mr[0]; Q1 += h * mr[1]; Q2 += h * mr[2]; Q3 += h * mr[3];
        Q4 += h * mr[4]; Q5 += h * mr[5]; Q6 += h * mr[6]; Q7 += h * mr[7];
        c  += h * uvec[i];
    }

    float* qb = qpT + (size_t)b * 384 + r;
#define STQ(k)                          \
    qb[(4 * k + 0) * 12] = Q##k.x;      \
    qb[(4 * k + 1) * 12] = Q##k.y;      \
    qb[(4 * k + 2) * 12] = Q##k.z;      \
    qb[(4 * k + 3) * 12] = Q##k.w;
    STQ(0) STQ(1) STQ(2) STQ(3) STQ(4) STQ(5) STQ(6) STQ(7)
#undef STQ

    cc[gt] = c;
    inten_out[gt] = iw;
}

// ---------------------------------------------------------------------------
// main_kernel: one block per batch b, 256 threads x 8 LEDs (two floatx4
// halves A/B, all named registers).  4 waves/block -> whole 1024-block grid
// is CU-resident (16 waves/CU).  6 uniform ds_read_b128 per j feed 8 LEDs.
// ---------------------------------------------------------------------------
__global__ void __launch_bounds__(256, 1) main_kernel(
    const float* __restrict__ ledf,     // [B,N,8]
    const float* __restrict__ ledp,     // [B,N,3]
    const float* __restrict__ prevp,    // [B,3]
    const int*   __restrict__ maskbits, // [N]
    const float* __restrict__ WkT,      // [32][12]
    const float* __restrict__ qpT,      // [B][32][12]
    const float* __restrict__ cc,       // [B*R]
    const float* __restrict__ sigp,     // [1]
    float* __restrict__ out)            // [B,R,N]
{
    const int b = blockIdx.x;
    const int tid = threadIdx.x;
    const int lane = tid & 63;
    const int wave = tid >> 6;          // 0..3
    const int n0 = tid * 8;

    __shared__ float sW[32 * 12];
    __shared__ float sQ[32 * 12];
    __shared__ float red[4 * 12];

    for (int i = tid; i < 384; i += 256) {
        sW[i] = WkT[i];
        sQ[i] = qpT[(size_t)b * 384 + i];
    }

    const float* __restrict__ ccb = cc + b * 12;
    const float sig = sigp[0];
    const float nfc = -0.5f / (sig * sig);
    const float p0 = prevp[b * 3 + 0];
    const float p1 = prevp[b * 3 + 1];
    const float p2 = prevp[b * 3 + 2];

    const floatx4* pf  = reinterpret_cast<const floatx4*>(ledf + ((size_t)b * N_ + n0) * 8);
    const floatx4* pp4 = reinterpret_cast<const floatx4*>(ledp + ((size_t)b * N_ + n0) * 3);
    const int4*    pm  = reinterpret_cast<const int4*>(maskbits + n0);

    const floatx4 F0 = pf[0],  F1 = pf[1],  F2 = pf[2],  F3 = pf[3];
    const floatx4 F4 = pf[4],  F5 = pf[5],  F6 = pf[6],  F7 = pf[7];
    const floatx4 F8 = pf[8],  F9 = pf[9],  F10 = pf[10], F11 = pf[11];
    const floatx4 F12 = pf[12], F13 = pf[13], F14 = pf[14], F15 = pf[15];
    const floatx4 pa0 = pp4[0], pa1 = pp4[1], pa2 = pp4[2];
    const floatx4 pa3 = pp4[3], pa4 = pp4[4], pa5 = pp4[5];
    const int4 mbA = pm[0], mbB = pm[1];

    // half A = LEDs 0-3, half B = LEDs 4-7 (transposed to across-LED vectors)
    const floatx4 XA0 = {F0.x, F2.x, F4.x, F6.x};
    const floatx4 XA1 = {F0.y, F2.y, F4.y, F6.y};
    const floatx4 XA2 = {F0.z, F2.z, F4.z, F6.z};
    const floatx4 XA3 = {F0.w, F2.w, F4.w, F6.w};
    const floatx4 XA4 = {F1.x, F3.x, F5.x, F7.x};
    const floatx4 XA5 = {F1.y, F3.y, F5.y, F7.y};
    const floatx4 XA6 = {F1.z, F3.z, F5.z, F7.z};
    const floatx4 XA7 = {F1.w, F3.w, F5.w, F7.w};
    const floatx4 XA8 = {pa0.x, pa0.w, pa1.z, pa2.y};
    const floatx4 XA9 = {pa0.y, pa1.x, pa1.w, pa2.z};
    const floatx4 XA10 = {pa0.z, pa1.y, pa2.x, pa2.w};
    const floatx4 XB0 = {F8.x, F10.x, F12.x, F14.x};
    const floatx4 XB1 = {F8.y, F10.y, F12.y, F14.y};
    const floatx4 XB2 = {F8.z, F10.z, F12.z, F14.z};
    const floatx4 XB3 = {F8.w, F10.w, F12.w, F14.w};
    const floatx4 XB4 = {F9.x, F11.x, F13.x, F15.x};
    const floatx4 XB5 = {F9.y, F11.y, F13.y, F15.y};
    const floatx4 XB6 = {F9.z, F11.z, F13.z, F15.z};
    const floatx4 XB7 = {F9.w, F11.w, F13.w, F15.w};
    const floatx4 XB8 = {pa3.x, pa3.w, pa4.z, pa5.y};
    const floatx4 XB9 = {pa3.y, pa4.x, pa4.w, pa5.z};
    const floatx4 XB10 = {pa3.z, pa4.y, pa5.x, pa5.w};

    const floatx4 DXA = p0 - XA8, DYA = p1 - XA9, DZA = p2 - XA10;
    const floatx4 BIASA = nfc * (DXA * DXA + DYA * DYA + DZA * DZA);
    const floatx4 DXB = p0 - XB8, DYB = p1 - XB9, DZB = p2 - XB10;
    const floatx4 BIASB = nfc * (DXB * DXB + DYB * DYB + DZB * DZB);

#define FOR_R(OP) OP(0) OP(1) OP(2) OP(3) OP(4) OP(5) OP(6) OP(7) OP(8) OP(9) OP(10) OP(11)
#define INIT_R(r) floatx4 AA##r = BIASA + ccb[r]; floatx4 AB##r = BIASB + ccb[r];
    FOR_R(INIT_R)

    __syncthreads();   // staging done

#pragma unroll 2
    for (int j = 0; j < 32; j++) {
        const floatx4 w0 = *reinterpret_cast<const floatx4*>(&sW[j * 12]);
        const floatx4 w1 = *reinterpret_cast<const floatx4*>(&sW[j * 12 + 4]);
        const floatx4 w2 = *reinterpret_cast<const floatx4*>(&sW[j * 12 + 8]); // {w8,w9,w10,bj}
        const floatx4 q0 = *reinterpret_cast<const floatx4*>(&sQ[j * 12]);
        const floatx4 q1 = *reinterpret_cast<const floatx4*>(&sQ[j * 12 + 4]);
        const floatx4 q2 = *reinterpret_cast<const floatx4*>(&sQ[j * 12 + 8]);

        floatx4 HA = {w2.w, w2.w, w2.w, w2.w};
        floatx4 HB = HA;
        HA += XA0 * w0.x;  HB += XB0 * w0.x;
        HA += XA1 * w0.y;  HB += XB1 * w0.y;
        HA += XA2 * w0.z;  HB += XB2 * w0.z;
        HA += XA3 * w0.w;  HB += XB3 * w0.w;
        HA += XA4 * w1.x;  HB += XB4 * w1.x;
        HA += XA5 * w1.y;  HB += XB5 * w1.y;
        HA += XA6 * w1.z;  HB += XB6 * w1.z;
        HA += XA7 * w1.w;  HB += XB7 * w1.w;
        HA += XA8 * w2.x;  HB += XB8 * w2.x;
        HA += XA9 * w2.y;  HB += XB9 * w2.y;
        HA += XA10 * w2.z; HB += XB10 * w2.z;
        HA.x = fmaxf(HA.x, 0.0f); HA.y = fmaxf(HA.y, 0.0f);
        HA.z = fmaxf(HA.z, 0.0f); HA.w = fmaxf(HA.w, 0.0f);
        HB.x = fmaxf(HB.x, 0.0f); HB.y = fmaxf(HB.y, 0.0f);
        HB.z = fmaxf(HB.z, 0.0f); HB.w = fmaxf(HB.w, 0.0f);

        AA0 += HA * q0.x;  AB0 += HB * q0.x;
        AA1 += HA * q0.y;  AB1 += HB * q0.y;
        AA2 += HA * q0.z;  AB2 += HB * q0.z;
        AA3 += HA * q0.w;  AB3 += HB * q0.w;
        AA4 += HA * q1.x;  AB4 += HB * q1.x;
        AA5 += HA * q1.y;  AB5 += HB * q1.y;
        AA6 += HA * q1.z;  AB6 += HB * q1.z;
        AA7 += HA * q1.w;  AB7 += HB * q1.w;
        AA8 += HA * q2.x;  AB8 += HB * q2.x;
        AA9 += HA * q2.y;  AB9 += HB * q2.y;
        AA10 += HA * q2.z; AB10 += HB * q2.z;
        AA11 += HA * q2.w; AB11 += HB * q2.w;
    }

#define MASK_R(r)                                            \
    AA##r.x = ((mbA.x >> r) & 1) ? AA##r.x : -FLT_MAX;       \
    AA##r.y = ((mbA.y >> r) & 1) ? AA##r.y : -FLT_MAX;       \
    AA##r.z = ((mbA.z >> r) & 1) ? AA##r.z : -FLT_MAX;       \
    AA##r.w = ((mbA.w >> r) & 1) ? AA##r.w : -FLT_MAX;       \
    AB##r.x = ((mbB.x >> r) & 1) ? AB##r.x : -FLT_MAX;       \
    AB##r.y = ((mbB.y >> r) & 1) ? AB##r.y : -FLT_MAX;       \
    AB##r.z = ((mbB.z >> r) & 1) ? AB##r.z : -FLT_MAX;       \
    AB##r.w = ((mbB.w >> r) & 1) ? AB##r.w : -FLT_MAX;
    FOR_R(MASK_R)

#define WMAX_R(r) {                                                     \
    float v = fmaxf(fmaxf(fmaxf(AA##r.x, AA##r.y), fmaxf(AA##r.z, AA##r.w)), \
                    fmaxf(fmaxf(AB##r.x, AB##r.y), fmaxf(AB##r.z, AB##r.w))); \
    _Pragma("unroll")                                                   \
    for (int off = 32; off >= 1; off >>= 1) v = fmaxf(v, __shfl_xor(v, off)); \
    if (lane == 0) red[wave * 12 + r] = v; }
    FOR_R(WMAX_R)
    __syncthreads();
#define FMAX_R(r) float M##r = red[r];                                  \
    { _Pragma("unroll")                                                 \
      for (int w = 1; w < 4; w++) M##r = fmaxf(M##r, red[w * 12 + r]); }
    FOR_R(FMAX_R)
    __syncthreads();

#define EXP_R(r) {                                                      \
    AA##r.x = __expf(AA##r.x - M##r); AA##r.y = __expf(AA##r.y - M##r); \
    AA##r.z = __expf(AA##r.z - M##r); AA##r.w = __expf(AA##r.w - M##r); \
    AB##r.x = __expf(AB##r.x - M##r); AB##r.y = __expf(AB##r.y - M##r); \
    AB##r.z = __expf(AB##r.z - M##r); AB##r.w = __expf(AB##r.w - M##r); \
    float v = ((AA##r.x + AA##r.y) + (AA##r.z + AA##r.w))               \
            + ((AB##r.x + AB##r.y) + (AB##r.z + AB##r.w));              \
    _Pragma("unroll")                                                   \
    for (int off = 32; off >= 1; off >>= 1) v += __shfl_xor(v, off);    \
    if (lane == 0) red[wave * 12 + r] = v; }
    FOR_R(EXP_R)
    __syncthreads();
#define FSUM_R(r) float S##r = red[r];                                  \
    { _Pragma("unroll")                                                 \
      for (int w = 1; w < 4; w++) S##r += red[w * 12 + r]; }            \
    S##r = 1.0f / S##r;
    FOR_R(FSUM_R)

    float* outp = out + (size_t)b * R_ * N_ + n0;
#define STORE_R(r) {                                                    \
    floatx4 vA = AA##r * S##r;                                          \
    floatx4 vB = AB##r * S##r;                                          \
    __builtin_nontemporal_store(vA, reinterpret_cast<floatx4*>(outp + (size_t)r * N_)); \
    __builtin_nontemporal_store(vB, reinterpret_cast<floatx4*>(outp + (size_t)r * N_ + 4)); }
    FOR_R(STORE_R)
}

// ---------------------------------------------------------------------------
extern "C" void kernel_launch(void* const* d_in, const int* in_sizes, int n_in,
                              void* d_out, int out_size, void* d_ws, size_t ws_size,
                              hipStream_t stream) {
    const float* rss  = (const float*)d_in[0];
    const float* ledf = (const float*)d_in[1];
    const float* ledp = (const float*)d_in[2];
    const float* prevp= (const float*)d_in[3];
    const int*   mask = (const int*)  d_in[4];
    const float* Wg1  = (const float*)d_in[5];
    const float* bg1  = (const float*)d_in[6];
    const float* Wg2  = (const float*)d_in[7];
    const float* bg2  = (const float*)d_in[8];
    const float* Wq1  = (const float*)d_in[9];
    const float* bq1  = (const float*)d_in[10];
    const float* Wq2  = (const float*)d_in[11];
    const float* bq2  = (const float*)d_in[12];
    const float* Wk1  = (const float*)d_in[13];
    const float* bk1  = (const float*)d_in[14];
    const float* Wk2  = (const float*)d_in[15];
    const float* bk2  = (const float*)d_in[16];
    const float* sigp = (const float*)d_in[17];

    float* out = (float*)d_out;
    float* inten = out + (size_t)B_ * R_ * N_;     // intensity_weight [B,R] tail

    float* qpT      = (float*)d_ws;                // [B][32][12]
    float* cc       = qpT + (size_t)B_ * 384;      // [B*R]
    int*   maskbits = (int*)(cc + B_ * R_);        // [N]
    float* Mmat     = (float*)(maskbits + N_);     // [32,32]
    float* uvec     = Mmat + 1024;                 // [32]
    float* vvec     = uvec + 32;                   // [32]
    float* k0p      = vvec + 32;                   // [1]
    float* WkT      = k0p + 4;                     // [32*12] (16B aligned)

    const_kernel<<<1, 1024, 0, stream>>>(Wq2, bq2, Wk2, bk2, Wk1, bk1,
                                         Mmat, uvec, vvec, k0p, WkT);

    prep_kernel<<<(B_ * R_ + 255) / 256, 256, 0, stream>>>(
        rss, Wg1, bg1, Wg2, bg2, Wq1, bq1,
        Mmat, uvec, vvec, k0p, mask, qpT, cc, maskbits, inten);

    main_kernel<<<B_, 256, 0, stream>>>(
        ledf, ledp, prevp, maskbits, WkT, qpT, cc, sigp, out);
}